// Round 1
// baseline (109.705 us; speedup 1.0000x reference)
//
#include <hip/hip_runtime.h>
#include <math.h>

// PLIF spiking neuron forward:
//   decay = sigmoid(a)
//   for t in 0..T-1:  mem = decay*mem + x[:,t]; s = (mem >= 1); mem = s ? 0 : mem
// Layout [B, T, C, H, W]: neuron index j in [0, C*H*W) is contiguous; time
// stride is C*H*W. One thread handles 4 adjacent neurons (float4) -> fully
// coalesced 16B/lane at every t, scan state lives in registers.

constexpr int T_STEPS = 32;
constexpr int CHW     = 128 * 32 * 32;   // 131072
constexpr int CHW4    = CHW / 4;         // 32768 float4 per (b, t) slab
constexpr int BATCH   = 16;

__global__ __launch_bounds__(256)
void plif_fwd_kernel(const float4* __restrict__ x,
                     const float*  __restrict__ a_ptr,
                     float4*       __restrict__ out)
{
    // decay in fp64 then round once to fp32: matches the correctly-rounded
    // fp32 sigmoid(5.0) that an accurate CPU reference produces. One flipped
    // spike fails the absmax check, so decay bits matter.
    const double a = (double)a_ptr[0];
    const float decay = (float)(1.0 / (1.0 + exp(-a)));

    const int tid = blockIdx.x * blockDim.x + threadIdx.x;
    const int b   = tid >> 15;            // tid / CHW4
    const int j   = tid & (CHW4 - 1);     // tid % CHW4
    if (b >= BATCH) return;

    const size_t base = (size_t)b * T_STEPS * CHW4 + (size_t)j;

    float mx = 0.0f, my = 0.0f, mz = 0.0f, mw = 0.0f;

    #pragma unroll 4
    for (int t = 0; t < T_STEPS; ++t) {
        const float4 xi = x[base + (size_t)t * CHW4];

        // Explicit round-to-nearest mul then add: forbid FMA contraction so
        // we bit-match a plain numpy/XLA-CPU mul+add sequence.
        mx = __fadd_rn(__fmul_rn(decay, mx), xi.x);
        my = __fadd_rn(__fmul_rn(decay, my), xi.y);
        mz = __fadd_rn(__fmul_rn(decay, mz), xi.z);
        mw = __fadd_rn(__fmul_rn(decay, mw), xi.w);

        float4 s;
        s.x = (mx >= 1.0f) ? 1.0f : 0.0f;
        s.y = (my >= 1.0f) ? 1.0f : 0.0f;
        s.z = (mz >= 1.0f) ? 1.0f : 0.0f;
        s.w = (mw >= 1.0f) ? 1.0f : 0.0f;

        // hard reset: mem * (1 - s) == (s ? +0.0f : mem) exactly
        mx = (s.x != 0.0f) ? 0.0f : mx;
        my = (s.y != 0.0f) ? 0.0f : my;
        mz = (s.z != 0.0f) ? 0.0f : mz;
        mw = (s.w != 0.0f) ? 0.0f : mw;

        out[base + (size_t)t * CHW4] = s;
    }
}

extern "C" void kernel_launch(void* const* d_in, const int* in_sizes, int n_in,
                              void* d_out, int out_size, void* d_ws, size_t ws_size,
                              hipStream_t stream)
{
    const float4* x     = (const float4*)d_in[0];
    const float*  a_ptr = (const float*)d_in[1];
    float4*       out   = (float4*)d_out;

    const int total_threads = BATCH * CHW4;        // 524288
    const int block = 256;
    const int grid  = total_threads / block;       // 2048, exact

    plif_fwd_kernel<<<grid, block, 0, stream>>>(x, a_ptr, out);
}

// Round 3
// 93.419 us; speedup vs baseline: 1.1743x; 1.1743x over previous
//
#include <hip/hip_runtime.h>
#include <math.h>

// PLIF spiking neuron forward:
//   decay = sigmoid(a)
//   for t in 0..T-1:  mem = decay*mem + x[:,t]; s = (mem >= 1); mem = s ? 0 : mem
// Layout [B, T, C, H, W]: neuron index j in [0, C*H*W) contiguous; time stride
// CHW. One thread owns 4 adjacent neurons (float4): coalesced 16B/lane every t,
// scan state in registers.
//
// R1: 109.7 us = 4.9 TB/s (78% of copy ceiling). Zero reuse within a replay,
// working set (512 MiB) > L3 (256 MiB) -> non-temporal both streams; unroll 8
// for deeper load pipelining. R2 fix: nontemporal builtins need a native clang
// vector type, not HIP_vector_type -> use ext_vector_type(4) float.

constexpr int T_STEPS = 32;
constexpr int CHW     = 128 * 32 * 32;   // 131072
constexpr int CHW4    = CHW / 4;         // 32768 float4 per (b, t) slab
constexpr int BATCH   = 16;

typedef float f32x4 __attribute__((ext_vector_type(4)));

__global__ __launch_bounds__(256)
void plif_fwd_kernel(const f32x4* __restrict__ x,
                     const float* __restrict__ a_ptr,
                     f32x4*       __restrict__ out)
{
    // decay computed in fp64 then rounded once: matches the correctly-rounded
    // fp32 sigmoid the CPU reference produces. One flipped spike fails.
    const double a = (double)a_ptr[0];
    const float decay = (float)(1.0 / (1.0 + exp(-a)));

    const int tid = blockIdx.x * blockDim.x + threadIdx.x;
    const int b   = tid >> 15;            // tid / CHW4
    const int j   = tid & (CHW4 - 1);     // tid % CHW4

    const f32x4* xp = x   + (size_t)b * T_STEPS * CHW4 + (size_t)j;
    f32x4*       op = out + (size_t)b * T_STEPS * CHW4 + (size_t)j;

    float mx = 0.0f, my = 0.0f, mz = 0.0f, mw = 0.0f;

    #pragma unroll 8
    for (int t = 0; t < T_STEPS; ++t) {
        const f32x4 xi = __builtin_nontemporal_load(xp + (size_t)t * CHW4);

        // Explicit rn mul then rn add: forbid FMA contraction so we bit-match
        // the reference's separate mul+add.
        mx = __fadd_rn(__fmul_rn(decay, mx), xi.x);
        my = __fadd_rn(__fmul_rn(decay, my), xi.y);
        mz = __fadd_rn(__fmul_rn(decay, mz), xi.z);
        mw = __fadd_rn(__fmul_rn(decay, mw), xi.w);

        f32x4 s;
        s.x = (mx >= 1.0f) ? 1.0f : 0.0f;
        s.y = (my >= 1.0f) ? 1.0f : 0.0f;
        s.z = (mz >= 1.0f) ? 1.0f : 0.0f;
        s.w = (mw >= 1.0f) ? 1.0f : 0.0f;

        // hard reset: mem * (1 - s) == (s ? +0.0f : mem) exactly
        mx = (s.x != 0.0f) ? 0.0f : mx;
        my = (s.y != 0.0f) ? 0.0f : my;
        mz = (s.z != 0.0f) ? 0.0f : mz;
        mw = (s.w != 0.0f) ? 0.0f : mw;

        __builtin_nontemporal_store(s, op + (size_t)t * CHW4);
    }
}

extern "C" void kernel_launch(void* const* d_in, const int* in_sizes, int n_in,
                              void* d_out, int out_size, void* d_ws, size_t ws_size,
                              hipStream_t stream)
{
    const f32x4* x     = (const f32x4*)d_in[0];
    const float* a_ptr = (const float*)d_in[1];
    f32x4*       out   = (f32x4*)d_out;

    const int total_threads = BATCH * CHW4;        // 524288
    const int block = 256;
    const int grid  = total_threads / block;       // 2048, exact

    plif_fwd_kernel<<<grid, block, 0, stream>>>(x, a_ptr, out);
}